// Round 12
// baseline (184.931 us; speedup 1.0000x reference)
//
#include <hip/hip_runtime.h>
#include <math.h>

#define NB   2
#define CIN  256
#define NN   6400
#define CKd  64
#define CVd  128
#define COd  256

using bf16   = __bf16;
using bf16x4 = __attribute__((ext_vector_type(4))) bf16;
using bf16x8 = __attribute__((ext_vector_type(8))) bf16;
using f32x4  = __attribute__((ext_vector_type(4))) float;

__device__ __forceinline__ void lds_cp16(const void* g, void* l) {
    __builtin_amdgcn_global_load_lds((const __attribute__((address_space(1))) void*)g,
                                     (__attribute__((address_space(3))) void*)l, 16, 0, 0);
}

// ---------------------------------------------------------------------------
// k/q/v projection (r16 structure, proven): prep folded in; weights
// reg-staged fp32, BN-scale applied during bf16 pack; split-K two-pass
// staging, 32 KB LDS, 4 blocks/CU.  q weights/bias pre-scaled by 0.125
// (natural-log domain -- attn uses __expf); softmax p = exp(s - 8).
// grid (100, 4, NB).
// ---------------------------------------------------------------------------
__launch_bounds__(256, 4)
__global__ void projkqv_kernel(const float* __restrict__ x, const float* __restrict__ y,
                               const float* __restrict__ fk_w, const float* __restrict__ fk_g,
                               const float* __restrict__ fk_b, const float* __restrict__ fk_m,
                               const float* __restrict__ fk_v,
                               const float* __restrict__ fq_w, const float* __restrict__ fq_g,
                               const float* __restrict__ fq_b, const float* __restrict__ fq_m,
                               const float* __restrict__ fq_v,
                               const float* __restrict__ fv_w, const float* __restrict__ fv_b,
                               bf16* __restrict__ kb, bf16* __restrict__ qb, bf16* __restrict__ vb)
{
    __shared__ __align__(16) bf16 sbuf[64 * 128];   // 16 KB src [n][c-half], XOR chunks
    __shared__ __align__(16) bf16 wbuf[64 * 128];   // 16 KB weights half, XOR chunks

    const int tid  = threadIdx.x;
    const int lane = tid & 63, wav = tid >> 6;
    const int l15  = lane & 15, quad = lane >> 4;
    const int b    = blockIdx.z, m = blockIdx.y;
    const int n0   = blockIdx.x * 64;
    const float QS = 0.125f;               // attn scale, natural-log domain

    const float* srcg = ((m == 0) ? x : y) + (size_t)b * CIN * NN;

    const int key = l15 & 7;
    f32x4 acc[4];
#pragma unroll
    for (int j = 0; j < 4; ++j) acc[j] = (f32x4){0.f, 0.f, 0.f, 0.f};

    for (int p = 0; p < 2; ++p) {
        if (p) __syncthreads();            // all waves done reading pass-0 bufs

        // weights half: reg-stage fp32 + BN-fold + cvt -> XOR LDS layout
        {
            const int r4  = lane >> 4;
            const int c16 = lane & 15;
#pragma unroll
            for (int i = 0; i < 4; ++i) {
                const int r  = wav * 16 + i * 4 + r4;
                const int cs = c16 ^ (r & 7);
                const float* ws = (m == 0) ? (fk_w + (size_t)r * CIN)
                                : (m == 1) ? (fq_w + (size_t)r * CIN)
                                : (fv_w + (size_t)((m - 2) * 64 + r) * CIN);
                const float4 w0 = *(const float4*)(ws + p * 128 + cs * 8);
                const float4 w1 = *(const float4*)(ws + p * 128 + cs * 8 + 4);
                float a = 1.0f;
                if (m == 0)      a = fk_g[r] * rsqrtf(fk_v[r] + 1e-5f);
                else if (m == 1) a = fq_g[r] * rsqrtf(fq_v[r] + 1e-5f) * QS;
                bf16x8 pk;
                pk[0] = (bf16)(w0.x * a); pk[1] = (bf16)(w0.y * a);
                pk[2] = (bf16)(w0.z * a); pk[3] = (bf16)(w0.w * a);
                pk[4] = (bf16)(w1.x * a); pk[5] = (bf16)(w1.y * a);
                pk[6] = (bf16)(w1.z * a); pk[7] = (bf16)(w1.w * a);
                *(bf16x8*)&wbuf[r * 128 + c16 * 8] = pk;
            }
        }
        // src half: load + cvt + packed b128 scatter (register transpose)
        {
            const int nl = (tid & 15) * 4;
            const int cq = tid >> 4;            // 0..15 local chunk
            const int cb = p * 128 + cq * 8;
            float4 v[8];
#pragma unroll
            for (int e = 0; e < 8; ++e)
                v[e] = *(const float4*)(srcg + (size_t)(cb + e) * NN + n0 + nl);
#pragma unroll
            for (int i = 0; i < 4; ++i) {
                const int n = nl + i;
                bf16x8 pk;
#pragma unroll
                for (int e = 0; e < 8; ++e) pk[e] = (bf16)(&v[e].x)[i];
                *(bf16x8*)&sbuf[n * 128 + ((cq ^ (n & 7)) * 8)] = pk;
            }
        }
        __syncthreads();                   // drain ds_writes

        if (m < 2) {
            const int arow = wav * 16 + l15;
#pragma unroll
            for (int k4 = 0; k4 < 16; k4 += 4) {
                const bf16x8 af = *(const bf16x8*)&sbuf[arow * 128 + (((k4 + quad) ^ key) * 8)];
#pragma unroll
                for (int nt = 0; nt < 4; ++nt) {
                    const int brow = nt * 16 + l15;
                    const bf16x8 bfw = *(const bf16x8*)&wbuf[brow * 128 + (((k4 + quad) ^ key) * 8)];
                    acc[nt] = __builtin_amdgcn_mfma_f32_16x16x32_bf16(af, bfw, acc[nt], 0, 0, 0);
                }
            }
        } else {
            const int arow = wav * 16 + l15;
#pragma unroll
            for (int k4 = 0; k4 < 16; k4 += 4) {
                const bf16x8 af = *(const bf16x8*)&wbuf[arow * 128 + (((k4 + quad) ^ key) * 8)];
#pragma unroll
                for (int nt = 0; nt < 4; ++nt) {
                    const int brow = nt * 16 + l15;
                    const bf16x8 bfy = *(const bf16x8*)&sbuf[brow * 128 + (((k4 + quad) ^ key) * 8)];
                    acc[nt] = __builtin_amdgcn_mfma_f32_16x16x32_bf16(af, bfy, acc[nt], 0, 0, 0);
                }
            }
        }
    }

    if (m < 2) {
        bf16* dst = (m == 0) ? kb : qb;
        const int nb = n0 + wav * 16;
#pragma unroll
        for (int nt = 0; nt < 4; ++nt) {
            float bv;
            {
                const int c = nt * 16 + l15;
                if (m == 0) {
                    const float a = fk_g[c] * rsqrtf(fk_v[c] + 1e-5f);
                    bv = fk_b[c] - fk_m[c] * a;
                } else {
                    const float a = fq_g[c] * rsqrtf(fq_v[c] + 1e-5f);
                    bv = (fq_b[c] - fq_m[c] * a) * QS;
                }
            }
#pragma unroll
            for (int r = 0; r < 4; ++r) {
                const int n = nb + quad * 4 + r;
                dst[((size_t)b * NN + n) * CKd + nt * 16 + l15] = (bf16)(acc[nt][r] + bv);
            }
        }
    } else {
        const int cv0 = (m - 2) * 64 + wav * 16;
#pragma unroll
        for (int r = 0; r < 4; ++r) {
            const int cv = cv0 + quad * 4 + r;
            const float bv = fv_b[cv];
#pragma unroll
            for (int nt = 0; nt < 4; ++nt)
                vb[((size_t)b * CVd + cv) * NN + n0 + nt * 16 + l15] = (bf16)(acc[nt][r] + bv);
        }
    }
}

// ---------------------------------------------------------------------------
// Flash attention r26 = r25 schedule with K MOVED OUT OF LDS:
//   r25 accounting: LDS read port ~2690 cyc/CU-iter (8 waves x 28
//   ds_read_b128 x ~12cyc) > MFMA pipe ~1860 -> LDS reads binding.
//   Every wave reads the whole 8 KB K tile, and kb's row-major layout means
//   MFMA K-fragments are loadable DIRECTLY from global at logical addrs
//   (no swizzle): kf0 = kb[(key0+kt*16+l15)*64 + quad*8], kf1 = +64B --
//   2 KB contiguous per kt, coalesced, L2-resident (FETCH shows 94% of
//   staging L2-absorbed).  Removes kbuf (16 KB), K-DMA, and 8/28 of the
//   per-wave LDS reads.  LDS 48 KB -> 3 blocks/CU (1.5x matrix-pipe feed).
//   V dbuf + single-barrier schedule of r25 UNCHANGED.
//   KS=7 -> grid 700 = 91% of 768-slot capacity (r23's fill lesson).
// 128 q/block (32 q/wave, 2 qtl), __expf softmax, setprio around PV.
// ---------------------------------------------------------------------------
__launch_bounds__(256, 3)
__global__ void attn_kernel(const bf16* __restrict__ qb, const bf16* __restrict__ kb,
                            const bf16* __restrict__ vb,
                            bf16* __restrict__ pO, float* __restrict__ pl, int KS)
{
    __shared__ __align__(16) bf16 vbuf[2][128 * 64];     // 32 KB  V double-buffer
    __shared__ __align__(16) bf16 p_lds[4][2][16][64];   // 16 KB  per-wave/qtl P

    const int lane = threadIdx.x & 63;
    const int wav  = threadIdx.x >> 6;
    const int l15  = lane & 15;
    const int quad = lane >> 4;
    const int r8   = lane >> 3;
    const int c_src = (lane & 7) ^ r8;
    const int sw   = l15 & 7;
    const int pkey = (l15 & 7) << 1;

    const int id    = blockIdx.x;
    const int ks    = id % KS;
    const int rst   = id / KS;
    const int b     = rst & 1;
    const int qtile = rst >> 1;          // 0..49
    const int q0    = qtile * 128 + wav * 32;

    const bf16* qrow = qb + (size_t)b * NN * CKd;
    const bf16* krow = kb + (size_t)b * NN * CKd;
    const bf16* vrow = vb + (size_t)b * CVd * NN;

    bf16x8 qf[2][2];                     // [qtl][s]
#pragma unroll
    for (int qtl = 0; qtl < 2; ++qtl)
#pragma unroll
        for (int s = 0; s < 2; ++s)
            qf[qtl][s] = *(const bf16x8*)(qrow + (size_t)(q0 + qtl * 16 + l15) * CKd + s * 32 + quad * 8);

    const float ZC = -8.0f;              // natural-log domain shift
    const f32x4 zini = (f32x4){ZC, ZC, ZC, ZC};

    f32x4 acc[2][8];
#pragma unroll
    for (int qtl = 0; qtl < 2; ++qtl)
#pragma unroll
        for (int cv = 0; cv < 8; ++cv) acc[qtl][cv] = (f32x4){0.f, 0.f, 0.f, 0.f};
    float psum[2] = {0.f, 0.f};

    const int t0 = (100 * ks) / KS;
    const int nt = (100 * (ks + 1)) / KS - t0;

    auto stageV = [&](int t, int bi) {
        const int key0 = t * 64;
#pragma unroll
        for (int g4 = 0; g4 < 4; ++g4) {
            const int g = wav * 4 + g4;
            lds_cp16(vrow + (size_t)(g * 8 + r8) * NN + key0 + c_src * 8,
                     &vbuf[bi][(g * 8) * 64]);
        }
    };

    stageV(t0, 0);
    __syncthreads();     // drain prologue DMA

    for (int t = 0; t < nt; ++t) {
        const int cur = t & 1;
        // next V tile staged at iter TOP: full-iteration latency cover
        if (t + 1 < nt) stageV(t0 + t + 1, cur ^ 1);
        const bf16* vcur = &vbuf[cur][0];
        const bf16* kt_base = krow + (size_t)(t0 + t) * 64 * CKd;

        // ---- S^T = K * Q^T, K-fragments straight from global (L2-hot) ----
        f32x4 s4[2][4];
#pragma unroll
        for (int kt = 0; kt < 4; ++kt) {
            const bf16* kr = kt_base + (size_t)(kt * 16 + l15) * CKd + quad * 8;
            const bf16x8 kf0 = *(const bf16x8*)(kr);
            const bf16x8 kf1 = *(const bf16x8*)(kr + 32);
#pragma unroll
            for (int qtl = 0; qtl < 2; ++qtl) {
                f32x4 z = zini;
                z = __builtin_amdgcn_mfma_f32_16x16x32_bf16(kf0, qf[qtl][0], z, 0, 0, 0);
                z = __builtin_amdgcn_mfma_f32_16x16x32_bf16(kf1, qf[qtl][1], z, 0, 0, 0);
                s4[qtl][kt] = z;
            }
        }

        // ---- p = exp(s - 8) via __expf, pack to per-wave/qtl p_lds ----
#pragma unroll
        for (int qtl = 0; qtl < 2; ++qtl) {
            float ps = 0.f;
#pragma unroll
            for (int kt = 0; kt < 4; ++kt) {
                bf16x4 pk;
#pragma unroll
                for (int r = 0; r < 4; ++r) {
                    const float p = __expf(s4[qtl][kt][r]);
                    ps += p;
                    pk[r] = (bf16)p;
                }
                *(bf16x4*)&p_lds[wav][qtl][l15][((kt * 4 + quad) ^ pkey) * 4] = pk;
            }
            psum[qtl] += ps;
        }

        // ---- ctx^T += V^T * P^T, both qtl; V(t) landed at prev iter end ----
        __builtin_amdgcn_s_setprio(1);
#pragma unroll
        for (int sp = 0; sp < 2; ++sp) {
            const bf16x8 pf0 = *(const bf16x8*)&p_lds[wav][0][l15][((sp * 8 + quad * 2) ^ pkey) * 4];
            const bf16x8 pf1 = *(const bf16x8*)&p_lds[wav][1][l15][((sp * 8 + quad * 2) ^ pkey) * 4];
#pragma unroll
            for (int cvt = 0; cvt < 8; ++cvt) {
                const int rr = cvt * 16 + l15;
                const bf16x8 vf = *(const bf16x8*)&vcur[rr * 64 + (((sp * 4 + quad) ^ sw) * 8)];
                acc[0][cvt] = __builtin_amdgcn_mfma_f32_16x16x32_bf16(vf, pf0, acc[0][cvt], 0, 0, 0);
                acc[1][cvt] = __builtin_amdgcn_mfma_f32_16x16x32_bf16(vf, pf1, acc[1][cvt], 0, 0, 0);
            }
        }
        __builtin_amdgcn_s_setprio(0);

        // ---- single barrier/iter: next V tile (issued at top) landed ----
        if (t + 1 < nt) { asm volatile("s_waitcnt vmcnt(0)" ::: "memory"); }
        __builtin_amdgcn_s_barrier();
    }

    // ---- epilogue: transpose acc through per-wave p_lds -> coalesced pO ----
    __syncthreads();
    bf16* tbuf = &p_lds[wav][0][0][0];   // per-wave 2048 bf16 = [16 rows][128]
    const size_t pb = (size_t)ks * NB + b;
#pragma unroll
    for (int qt = 0; qt < 2; ++qt) {
        psum[qt] += __shfl_xor(psum[qt], 16);
        psum[qt] += __shfl_xor(psum[qt], 32);
#pragma unroll
        for (int cvt = 0; cvt < 8; ++cvt) {
            bf16x4 pk;
#pragma unroll
            for (int r = 0; r < 4; ++r) pk[r] = (bf16)acc[qt][cvt][r];
            const int u = (cvt * 4 + quad) ^ (l15 << 1);
            *(bf16x4*)&tbuf[l15 * 128 + u * 4] = pk;
        }
#pragma unroll
        for (int j = 0; j < 4; ++j) {
            const int row = j * 4 + (lane >> 4);
            const int g   = ((lane & 15) * 2) ^ ((row & 15) << 1);
            const bf16x8 vv = *(const bf16x8*)&tbuf[row * 128 + g * 4];
            *(bf16x8*)(pO + (pb * NN + q0 + qt * 16) * CVd + j * 512 + lane * 8) = vv;
        }
        if (quad == 0) pl[pb * NN + q0 + qt * 16 + l15] = psum[qt];
    }
}

// ---------------------------------------------------------------------------
// Fused combine + output projection (r16/r17, proven): W_w reg-staged
// fp32+cvt, phase-1 KS-chunk accumulation with 1-deep prefetch, two 128-co
// passes, 40 KB LDS -> 4 blocks/CU.  out = gamma*(W.ctx + W_b) + x.
// grid (200, NB).
// ---------------------------------------------------------------------------
__launch_bounds__(256, 4)
__global__ void outproj_kernel(const bf16* __restrict__ pO, const float* __restrict__ pl,
                               const float* __restrict__ W_w, const float* __restrict__ W_b,
                               const float* __restrict__ x, const float* __restrict__ gam,
                               float* __restrict__ out, int KS)
{
    __shared__ __align__(16) bf16 wbuf[128 * 128];   // 32 KB (co half)
    __shared__ __align__(16) bf16 cbuf[32 * 128];    // 8 KB

    const int tid  = threadIdx.x;
    const int lane = tid & 63, wav = tid >> 6;
    const int l15  = lane & 15, quad = lane >> 4;
    const int b    = blockIdx.y;
    const int n0   = blockIdx.x * 32;

    auto stage_w = [&](int p) {
        const int r4 = lane >> 4;
        const int c16 = lane & 15;
#pragma unroll
        for (int i = 0; i < 8; ++i) {
            const int r  = wav * 32 + i * 4 + r4;
            const int cs = c16 ^ (r & 7);
            const float* ws = W_w + (size_t)(p * 128 + r) * CVd + cs * 8;
            const float4 w0 = *(const float4*)(ws);
            const float4 w1 = *(const float4*)(ws + 4);
            bf16x8 pk;
            pk[0] = (bf16)w0.x; pk[1] = (bf16)w0.y; pk[2] = (bf16)w0.z; pk[3] = (bf16)w0.w;
            pk[4] = (bf16)w1.x; pk[5] = (bf16)w1.y; pk[6] = (bf16)w1.z; pk[7] = (bf16)w1.w;
            *(bf16x8*)&wbuf[r * 128 + c16 * 8] = pk;
        }
    };
    stage_w(0);

    // ---- phase 1: accumulate KS chunks of pO, 16 vals/thread, prefetched ----
    const int tn = tid >> 3;
    const int tc = (tid & 7) * 16;
    const size_t kstr = (size_t)NB * NN * CVd;
    const bf16* src0 = pO + ((size_t)b * NN + n0 + tn) * CVd + tc;
    float vacc[16];
#pragma unroll
    for (int i = 0; i < 16; ++i) vacc[i] = 0.f;
    float L = 0.f;

    bf16x8 c0 = *(const bf16x8*)(src0);
    bf16x8 c1 = *(const bf16x8*)(src0 + 8);
    for (int ksi = 0; ksi < KS; ++ksi) {
        bf16x8 nx0 = c0, nx1 = c1;
        if (ksi + 1 < KS) {
            const bf16* s = src0 + (size_t)(ksi + 1) * kstr;
            nx0 = *(const bf16x8*)(s);
            nx1 = *(const bf16x8*)(s + 8);
        }
        L += pl[(size_t)(ksi * NB + b) * NN + n0 + tn];
#pragma unroll
        for (int e = 0; e < 8; ++e) vacc[e]     += (float)c0[e];
#pragma unroll
        for (int e = 0; e < 8; ++e) vacc[8 + e] += (float)c1[e];
        c0 = nx0; c1 = nx1;
    }
    {
        const float rL = 1.0f / L;
#pragma unroll
        for (int j = 0; j < 2; ++j) {
            bf16x8 o;
#pragma unroll
            for (int e = 0; e < 8; ++e) o[e] = (bf16)(vacc[j * 8 + e] * rL);
            const int c = (tid & 7) * 2 + j;
            *(bf16x8*)&cbuf[tn * 128 + ((c ^ (tn & 7)) * 8)] = o;
        }
    }
    __syncthreads();   // drains wbuf half-0 + cbuf ds_writes

    const float gm = gam[0];

    auto mfma_pass = [&](f32x4 (&acc)[2][2]) {
#pragma unroll
        for (int i = 0; i < 2; ++i)
#pragma unroll
            for (int j = 0; j < 2; ++j) acc[i][j] = (f32x4){0.f, 0.f, 0.f, 0.f};
#pragma unroll
        for (int kk = 0; kk < 4; ++kk) {
#pragma unroll
            for (int cot = 0; cot < 2; ++cot) {
                const int arow = wav * 32 + cot * 16 + l15;
                const bf16x8 af = *(const bf16x8*)&wbuf[arow * 128 + (((kk * 4 + quad) ^ (arow & 7)) * 8)];
#pragma unroll
                for (int nt = 0; nt < 2; ++nt) {
                    const int brow = nt * 16 + l15;
                    const bf16x8 bfc = *(const bf16x8*)&cbuf[brow * 128 + (((kk * 4 + quad) ^ (brow & 7)) * 8)];
                    acc[cot][nt] = __builtin_amdgcn_mfma_f32_16x16x32_bf16(af, bfc, acc[cot][nt], 0, 0, 0);
                }
            }
        }
    };
    auto store_pass = [&](const f32x4 (&acc)[2][2], int p) {
#pragma unroll
        for (int cot = 0; cot < 2; ++cot)
#pragma unroll
            for (int r = 0; r < 4; ++r) {
                const int co = p * 128 + wav * 32 + cot * 16 + quad * 4 + r;
                const float bv = W_b[co];
#pragma unroll
                for (int nt = 0; nt < 2; ++nt) {
                    const int n = n0 + nt * 16 + l15;
                    const size_t a = ((size_t)b * COd + co) * NN + n;
                    out[a] = gm * (acc[cot][nt][r] + bv) + x[a];
                }
            }
    };

    f32x4 acc0[2][2];
    mfma_pass(acc0);
    __syncthreads();          // all waves done reading wbuf half 0
    stage_w(1);               // issue half-1 writes ...
    store_pass(acc0, 0);      // ... overlapped with half-0 stores
    __syncthreads();          // drain half-1 ds_writes
    f32x4 acc1[2][2];
    mfma_pass(acc1);
    store_pass(acc1, 1);
}

// ---------------------------------------------------------------------------
extern "C" void kernel_launch(void* const* d_in, const int* in_sizes, int n_in,
                              void* d_out, int out_size, void* d_ws, size_t ws_size,
                              hipStream_t stream)
{
    const float* x     = (const float*)d_in[0];
    const float* y     = (const float*)d_in[1];
    const float* fk_w  = (const float*)d_in[2];
    const float* fk_g  = (const float*)d_in[3];
    const float* fk_b  = (const float*)d_in[4];
    const float* fk_m  = (const float*)d_in[5];
    const float* fk_v  = (const float*)d_in[6];
    const float* fq_w  = (const float*)d_in[7];
    const float* fq_g  = (const float*)d_in[8];
    const float* fq_b  = (const float*)d_in[9];
    const float* fq_m  = (const float*)d_in[10];
    const float* fq_v  = (const float*)d_in[11];
    const float* fv_w  = (const float*)d_in[12];
    const float* fv_b  = (const float*)d_in[13];
    const float* W_w   = (const float*)d_in[14];
    const float* W_b   = (const float*)d_in[15];
    const float* gamma = (const float*)d_in[16];
    float* out = (float*)d_out;

    char* ws = (char*)d_ws;
    size_t off = 0;
    auto carve = [&](size_t bytes) -> char* {
        char* p = ws + off;
        off = (off + bytes + 255) & ~(size_t)255;
        return p;
    };

    bf16*  kb   = (bf16*)carve((size_t)NB * NN * CKd * 2);
    bf16*  qbuf = (bf16*)carve((size_t)NB * NN * CKd * 2);
    bf16*  vb   = (bf16*)carve((size_t)NB * CVd * NN * 2);

    const size_t region = ws_size - off;
    const size_t per_ks = (size_t)NB * NN * CVd * 2 + (size_t)NB * NN * 4 + 512;
    int KS = 1;
    {
        // KS=7 -> attn grid 700 = 91% of the 768-slot capacity (3 blocks/CU
        // at 48 KB LDS), one dispatch round.
        const int cand[5] = {7, 5, 4, 2, 1};
        for (int i = 0; i < 5; ++i)
            if ((size_t)cand[i] * per_ks <= region) { KS = cand[i]; break; }
    }
    bf16*  pO = (bf16*)carve((size_t)KS * NB * NN * CVd * 2);
    float* pl = (float*)carve((size_t)KS * NB * NN * 4);

    const dim3 blk(256);
    projkqv_kernel<<<dim3(100, 4, NB), blk, 0, stream>>>(x, y,
                                                         fk_w, fk_g, fk_b, fk_m, fk_v,
                                                         fq_w, fq_g, fq_b, fq_m, fq_v,
                                                         fv_w, fv_b, kb, qbuf, vb);
    attn_kernel<<<dim3(50 * NB * KS), blk, 0, stream>>>(qbuf, kb, vb, pO, pl, KS);
    outproj_kernel<<<dim3(200, NB), blk, 0, stream>>>(pO, pl, W_w, W_b, x, gamma, out, KS);
}

// Round 13
// 159.424 us; speedup vs baseline: 1.1600x; 1.1600x over previous
//
#include <hip/hip_runtime.h>
#include <math.h>

#define NB   2
#define CIN  256
#define NN   6400
#define CKd  64
#define CVd  128
#define COd  256

using bf16   = __bf16;
using bf16x4 = __attribute__((ext_vector_type(4))) bf16;
using bf16x8 = __attribute__((ext_vector_type(8))) bf16;
using f32x4  = __attribute__((ext_vector_type(4))) float;

__device__ __forceinline__ void lds_cp16(const void* g, void* l) {
    __builtin_amdgcn_global_load_lds((const __attribute__((address_space(1))) void*)g,
                                     (__attribute__((address_space(3))) void*)l, 16, 0, 0);
}

// ---------------------------------------------------------------------------
// k/q/v projection (r16 structure, proven): prep folded in; weights
// reg-staged fp32, BN-scale applied during bf16 pack; split-K two-pass
// staging, 32 KB LDS, 4 blocks/CU.  q weights/bias pre-scaled by 0.125
// (natural-log domain -- attn uses __expf); softmax p = exp(s - 8).
// grid (100, 4, NB).
// ---------------------------------------------------------------------------
__launch_bounds__(256, 4)
__global__ void projkqv_kernel(const float* __restrict__ x, const float* __restrict__ y,
                               const float* __restrict__ fk_w, const float* __restrict__ fk_g,
                               const float* __restrict__ fk_b, const float* __restrict__ fk_m,
                               const float* __restrict__ fk_v,
                               const float* __restrict__ fq_w, const float* __restrict__ fq_g,
                               const float* __restrict__ fq_b, const float* __restrict__ fq_m,
                               const float* __restrict__ fq_v,
                               const float* __restrict__ fv_w, const float* __restrict__ fv_b,
                               bf16* __restrict__ kb, bf16* __restrict__ qb, bf16* __restrict__ vb)
{
    __shared__ __align__(16) bf16 sbuf[64 * 128];   // 16 KB src [n][c-half], XOR chunks
    __shared__ __align__(16) bf16 wbuf[64 * 128];   // 16 KB weights half, XOR chunks

    const int tid  = threadIdx.x;
    const int lane = tid & 63, wav = tid >> 6;
    const int l15  = lane & 15, quad = lane >> 4;
    const int b    = blockIdx.z, m = blockIdx.y;
    const int n0   = blockIdx.x * 64;
    const float QS = 0.125f;               // attn scale, natural-log domain

    const float* srcg = ((m == 0) ? x : y) + (size_t)b * CIN * NN;

    const int key = l15 & 7;
    f32x4 acc[4];
#pragma unroll
    for (int j = 0; j < 4; ++j) acc[j] = (f32x4){0.f, 0.f, 0.f, 0.f};

    for (int p = 0; p < 2; ++p) {
        if (p) __syncthreads();            // all waves done reading pass-0 bufs

        // weights half: reg-stage fp32 + BN-fold + cvt -> XOR LDS layout
        {
            const int r4  = lane >> 4;
            const int c16 = lane & 15;
#pragma unroll
            for (int i = 0; i < 4; ++i) {
                const int r  = wav * 16 + i * 4 + r4;
                const int cs = c16 ^ (r & 7);
                const float* ws = (m == 0) ? (fk_w + (size_t)r * CIN)
                                : (m == 1) ? (fq_w + (size_t)r * CIN)
                                : (fv_w + (size_t)((m - 2) * 64 + r) * CIN);
                const float4 w0 = *(const float4*)(ws + p * 128 + cs * 8);
                const float4 w1 = *(const float4*)(ws + p * 128 + cs * 8 + 4);
                float a = 1.0f;
                if (m == 0)      a = fk_g[r] * rsqrtf(fk_v[r] + 1e-5f);
                else if (m == 1) a = fq_g[r] * rsqrtf(fq_v[r] + 1e-5f) * QS;
                bf16x8 pk;
                pk[0] = (bf16)(w0.x * a); pk[1] = (bf16)(w0.y * a);
                pk[2] = (bf16)(w0.z * a); pk[3] = (bf16)(w0.w * a);
                pk[4] = (bf16)(w1.x * a); pk[5] = (bf16)(w1.y * a);
                pk[6] = (bf16)(w1.z * a); pk[7] = (bf16)(w1.w * a);
                *(bf16x8*)&wbuf[r * 128 + c16 * 8] = pk;
            }
        }
        // src half: load + cvt + packed b128 scatter (register transpose)
        {
            const int nl = (tid & 15) * 4;
            const int cq = tid >> 4;            // 0..15 local chunk
            const int cb = p * 128 + cq * 8;
            float4 v[8];
#pragma unroll
            for (int e = 0; e < 8; ++e)
                v[e] = *(const float4*)(srcg + (size_t)(cb + e) * NN + n0 + nl);
#pragma unroll
            for (int i = 0; i < 4; ++i) {
                const int n = nl + i;
                bf16x8 pk;
#pragma unroll
                for (int e = 0; e < 8; ++e) pk[e] = (bf16)(&v[e].x)[i];
                *(bf16x8*)&sbuf[n * 128 + ((cq ^ (n & 7)) * 8)] = pk;
            }
        }
        __syncthreads();                   // drain ds_writes

        if (m < 2) {
            const int arow = wav * 16 + l15;
#pragma unroll
            for (int k4 = 0; k4 < 16; k4 += 4) {
                const bf16x8 af = *(const bf16x8*)&sbuf[arow * 128 + (((k4 + quad) ^ key) * 8)];
#pragma unroll
                for (int nt = 0; nt < 4; ++nt) {
                    const int brow = nt * 16 + l15;
                    const bf16x8 bfw = *(const bf16x8*)&wbuf[brow * 128 + (((k4 + quad) ^ key) * 8)];
                    acc[nt] = __builtin_amdgcn_mfma_f32_16x16x32_bf16(af, bfw, acc[nt], 0, 0, 0);
                }
            }
        } else {
            const int arow = wav * 16 + l15;
#pragma unroll
            for (int k4 = 0; k4 < 16; k4 += 4) {
                const bf16x8 af = *(const bf16x8*)&wbuf[arow * 128 + (((k4 + quad) ^ key) * 8)];
#pragma unroll
                for (int nt = 0; nt < 4; ++nt) {
                    const int brow = nt * 16 + l15;
                    const bf16x8 bfy = *(const bf16x8*)&sbuf[brow * 128 + (((k4 + quad) ^ key) * 8)];
                    acc[nt] = __builtin_amdgcn_mfma_f32_16x16x32_bf16(af, bfy, acc[nt], 0, 0, 0);
                }
            }
        }
    }

    if (m < 2) {
        bf16* dst = (m == 0) ? kb : qb;
        const int nb = n0 + wav * 16;
#pragma unroll
        for (int nt = 0; nt < 4; ++nt) {
            float bv;
            {
                const int c = nt * 16 + l15;
                if (m == 0) {
                    const float a = fk_g[c] * rsqrtf(fk_v[c] + 1e-5f);
                    bv = fk_b[c] - fk_m[c] * a;
                } else {
                    const float a = fq_g[c] * rsqrtf(fq_v[c] + 1e-5f);
                    bv = (fq_b[c] - fq_m[c] * a) * QS;
                }
            }
#pragma unroll
            for (int r = 0; r < 4; ++r) {
                const int n = nb + quad * 4 + r;
                dst[((size_t)b * NN + n) * CKd + nt * 16 + l15] = (bf16)(acc[nt][r] + bv);
            }
        }
    } else {
        const int cv0 = (m - 2) * 64 + wav * 16;
#pragma unroll
        for (int r = 0; r < 4; ++r) {
            const int cv = cv0 + quad * 4 + r;
            const float bv = fv_b[cv];
#pragma unroll
            for (int nt = 0; nt < 4; ++nt)
                vb[((size_t)b * CVd + cv) * NN + n0 + nt * 16 + l15] = (bf16)(acc[nt][r] + bv);
        }
    }
}

// ---------------------------------------------------------------------------
// Flash attention r27 = r25 EXACT REVERT (session-best: attn 45.4, wall
// 159.6) + setprio(1) extended to the QK MFMA cluster (m191: +4-7%).
//   r26's K-from-global REGRESSED 45.4 -> 72.5: MFMA operands fed from
//   VMEM (~200cyc L2) instead of LDS (~30cyc) serialize each QK cluster
//   behind a vmcnt drain; 2.6 blocks/CU can't hide it (MfmaUtil 26 -> 16).
//   Lesson: MFMA operands must come from LDS/registers on gfx950.
// Structure (r25, proven): V double-buffered, both stages issued at iter
// TOP (full-iter latency cover), ONE barrier/iter (vmcnt(0)+s_barrier at
// iter end); p_lds per-wave-private (no barrier).  LDS 64 KB (K dbuf 16 +
// V dbuf 32 + p_lds 16) -> 2 blocks/CU, capacity 512; KS=5 -> grid 500 =
// 98% fill.  128 q/block (32 q/wave, 2 qtl), __expf softmax.
// ---------------------------------------------------------------------------
__launch_bounds__(256, 2)
__global__ void attn_kernel(const bf16* __restrict__ qb, const bf16* __restrict__ kb,
                            const bf16* __restrict__ vb,
                            bf16* __restrict__ pO, float* __restrict__ pl, int KS)
{
    __shared__ __align__(16) bf16 kbuf[2][64 * 64];      // 16 KB  K double-buffer
    __shared__ __align__(16) bf16 vbuf[2][128 * 64];     // 32 KB  V double-buffer
    __shared__ __align__(16) bf16 p_lds[4][2][16][64];   // 16 KB  per-wave/qtl P

    const int lane = threadIdx.x & 63;
    const int wav  = threadIdx.x >> 6;
    const int l15  = lane & 15;
    const int quad = lane >> 4;
    const int r8   = lane >> 3;
    const int c_src = (lane & 7) ^ r8;
    const int sw   = l15 & 7;
    const int pkey = (l15 & 7) << 1;

    const int id    = blockIdx.x;
    const int ks    = id % KS;
    const int rst   = id / KS;
    const int b     = rst & 1;
    const int qtile = rst >> 1;          // 0..49
    const int q0    = qtile * 128 + wav * 32;

    const bf16* qrow = qb + (size_t)b * NN * CKd;
    const bf16* krow = kb + (size_t)b * NN * CKd;
    const bf16* vrow = vb + (size_t)b * CVd * NN;

    bf16x8 qf[2][2];                     // [qtl][s]
#pragma unroll
    for (int qtl = 0; qtl < 2; ++qtl)
#pragma unroll
        for (int s = 0; s < 2; ++s)
            qf[qtl][s] = *(const bf16x8*)(qrow + (size_t)(q0 + qtl * 16 + l15) * CKd + s * 32 + quad * 8);

    const float ZC = -8.0f;              // natural-log domain shift
    const f32x4 zini = (f32x4){ZC, ZC, ZC, ZC};

    f32x4 acc[2][8];
#pragma unroll
    for (int qtl = 0; qtl < 2; ++qtl)
#pragma unroll
        for (int cv = 0; cv < 8; ++cv) acc[qtl][cv] = (f32x4){0.f, 0.f, 0.f, 0.f};
    float psum[2] = {0.f, 0.f};

    const int t0 = (100 * ks) / KS;
    const int nt = (100 * (ks + 1)) / KS - t0;

    auto stageK = [&](int t, int bi) {
        const int key0 = t * 64;
        lds_cp16(krow + (size_t)(key0 + wav * 8 + r8) * CKd + c_src * 8,
                 &kbuf[bi][(wav * 8) * 64]);
        lds_cp16(krow + (size_t)(key0 + (wav + 4) * 8 + r8) * CKd + c_src * 8,
                 &kbuf[bi][((wav + 4) * 8) * 64]);
    };
    auto stageV = [&](int t, int bi) {
        const int key0 = t * 64;
#pragma unroll
        for (int g4 = 0; g4 < 4; ++g4) {
            const int g = wav * 4 + g4;
            lds_cp16(vrow + (size_t)(g * 8 + r8) * NN + key0 + c_src * 8,
                     &vbuf[bi][(g * 8) * 64]);
        }
    };

    stageK(t0, 0);
    stageV(t0, 0);
    __syncthreads();     // drain prologue DMA

    for (int t = 0; t < nt; ++t) {
        const int cur = t & 1;
        // next-tile K+V staged at iter TOP: full-iteration latency cover
        if (t + 1 < nt) { stageK(t0 + t + 1, cur ^ 1); stageV(t0 + t + 1, cur ^ 1); }
        const bf16* kcur = &kbuf[cur][0];
        const bf16* vcur = &vbuf[cur][0];

        // ---- S^T = K * Q^T for both qtl subtiles, C-init = shift ----
        f32x4 s4[2][4];
        __builtin_amdgcn_s_setprio(1);
#pragma unroll
        for (int kt = 0; kt < 4; ++kt) {
            const int rr = kt * 16 + l15;
            const bf16x8 kf0 = *(const bf16x8*)&kcur[rr * 64 + ((quad ^ sw) * 8)];
            const bf16x8 kf1 = *(const bf16x8*)&kcur[rr * 64 + (((4 + quad) ^ sw) * 8)];
#pragma unroll
            for (int qtl = 0; qtl < 2; ++qtl) {
                f32x4 z = zini;
                z = __builtin_amdgcn_mfma_f32_16x16x32_bf16(kf0, qf[qtl][0], z, 0, 0, 0);
                z = __builtin_amdgcn_mfma_f32_16x16x32_bf16(kf1, qf[qtl][1], z, 0, 0, 0);
                s4[qtl][kt] = z;
            }
        }
        __builtin_amdgcn_s_setprio(0);

        // ---- p = exp(s - 8) via __expf, pack to per-wave/qtl p_lds ----
#pragma unroll
        for (int qtl = 0; qtl < 2; ++qtl) {
            float ps = 0.f;
#pragma unroll
            for (int kt = 0; kt < 4; ++kt) {
                bf16x4 pk;
#pragma unroll
                for (int r = 0; r < 4; ++r) {
                    const float p = __expf(s4[qtl][kt][r]);
                    ps += p;
                    pk[r] = (bf16)p;
                }
                *(bf16x4*)&p_lds[wav][qtl][l15][((kt * 4 + quad) ^ pkey) * 4] = pk;
            }
            psum[qtl] += ps;
        }

        // ---- ctx^T += V^T * P^T, both qtl; V(t) landed at prev iter end ----
        __builtin_amdgcn_s_setprio(1);
#pragma unroll
        for (int sp = 0; sp < 2; ++sp) {
            const bf16x8 pf0 = *(const bf16x8*)&p_lds[wav][0][l15][((sp * 8 + quad * 2) ^ pkey) * 4];
            const bf16x8 pf1 = *(const bf16x8*)&p_lds[wav][1][l15][((sp * 8 + quad * 2) ^ pkey) * 4];
#pragma unroll
            for (int cvt = 0; cvt < 8; ++cvt) {
                const int rr = cvt * 16 + l15;
                const bf16x8 vf = *(const bf16x8*)&vcur[rr * 64 + (((sp * 4 + quad) ^ sw) * 8)];
                acc[0][cvt] = __builtin_amdgcn_mfma_f32_16x16x32_bf16(vf, pf0, acc[0][cvt], 0, 0, 0);
                acc[1][cvt] = __builtin_amdgcn_mfma_f32_16x16x32_bf16(vf, pf1, acc[1][cvt], 0, 0, 0);
            }
        }
        __builtin_amdgcn_s_setprio(0);

        // ---- single barrier/iter: next tile's DMAs (issued at top) landed ----
        if (t + 1 < nt) { asm volatile("s_waitcnt vmcnt(0)" ::: "memory"); }
        __builtin_amdgcn_s_barrier();
    }

    // ---- epilogue: transpose acc through per-wave p_lds -> coalesced pO ----
    __syncthreads();
    bf16* tbuf = &p_lds[wav][0][0][0];   // per-wave 2048 bf16 = [16 rows][128]
    const size_t pb = (size_t)ks * NB + b;
#pragma unroll
    for (int qt = 0; qt < 2; ++qt) {
        psum[qt] += __shfl_xor(psum[qt], 16);
        psum[qt] += __shfl_xor(psum[qt], 32);
#pragma unroll
        for (int cvt = 0; cvt < 8; ++cvt) {
            bf16x4 pk;
#pragma unroll
            for (int r = 0; r < 4; ++r) pk[r] = (bf16)acc[qt][cvt][r];
            const int u = (cvt * 4 + quad) ^ (l15 << 1);
            *(bf16x4*)&tbuf[l15 * 128 + u * 4] = pk;
        }
#pragma unroll
        for (int j = 0; j < 4; ++j) {
            const int row = j * 4 + (lane >> 4);
            const int g   = ((lane & 15) * 2) ^ ((row & 15) << 1);
            const bf16x8 vv = *(const bf16x8*)&tbuf[row * 128 + g * 4];
            *(bf16x8*)(pO + (pb * NN + q0 + qt * 16) * CVd + j * 512 + lane * 8) = vv;
        }
        if (quad == 0) pl[pb * NN + q0 + qt * 16 + l15] = psum[qt];
    }
}

// ---------------------------------------------------------------------------
// Fused combine + output projection (r16/r17, proven): W_w reg-staged
// fp32+cvt, phase-1 KS-chunk accumulation with 1-deep prefetch, two 128-co
// passes, 40 KB LDS -> 4 blocks/CU.  out = gamma*(W.ctx + W_b) + x.
// grid (200, NB).
// ---------------------------------------------------------------------------
__launch_bounds__(256, 4)
__global__ void outproj_kernel(const bf16* __restrict__ pO, const float* __restrict__ pl,
                               const float* __restrict__ W_w, const float* __restrict__ W_b,
                               const float* __restrict__ x, const float* __restrict__ gam,
                               float* __restrict__ out, int KS)
{
    __shared__ __align__(16) bf16 wbuf[128 * 128];   // 32 KB (co half)
    __shared__ __align__(16) bf16 cbuf[32 * 128];    // 8 KB

    const int tid  = threadIdx.x;
    const int lane = tid & 63, wav = tid >> 6;
    const int l15  = lane & 15, quad = lane >> 4;
    const int b    = blockIdx.y;
    const int n0   = blockIdx.x * 32;

    auto stage_w = [&](int p) {
        const int r4 = lane >> 4;
        const int c16 = lane & 15;
#pragma unroll
        for (int i = 0; i < 8; ++i) {
            const int r  = wav * 32 + i * 4 + r4;
            const int cs = c16 ^ (r & 7);
            const float* ws = W_w + (size_t)(p * 128 + r) * CVd + cs * 8;
            const float4 w0 = *(const float4*)(ws);
            const float4 w1 = *(const float4*)(ws + 4);
            bf16x8 pk;
            pk[0] = (bf16)w0.x; pk[1] = (bf16)w0.y; pk[2] = (bf16)w0.z; pk[3] = (bf16)w0.w;
            pk[4] = (bf16)w1.x; pk[5] = (bf16)w1.y; pk[6] = (bf16)w1.z; pk[7] = (bf16)w1.w;
            *(bf16x8*)&wbuf[r * 128 + c16 * 8] = pk;
        }
    };
    stage_w(0);

    // ---- phase 1: accumulate KS chunks of pO, 16 vals/thread, prefetched ----
    const int tn = tid >> 3;
    const int tc = (tid & 7) * 16;
    const size_t kstr = (size_t)NB * NN * CVd;
    const bf16* src0 = pO + ((size_t)b * NN + n0 + tn) * CVd + tc;
    float vacc[16];
#pragma unroll
    for (int i = 0; i < 16; ++i) vacc[i] = 0.f;
    float L = 0.f;

    bf16x8 c0 = *(const bf16x8*)(src0);
    bf16x8 c1 = *(const bf16x8*)(src0 + 8);
    for (int ksi = 0; ksi < KS; ++ksi) {
        bf16x8 nx0 = c0, nx1 = c1;
        if (ksi + 1 < KS) {
            const bf16* s = src0 + (size_t)(ksi + 1) * kstr;
            nx0 = *(const bf16x8*)(s);
            nx1 = *(const bf16x8*)(s + 8);
        }
        L += pl[(size_t)(ksi * NB + b) * NN + n0 + tn];
#pragma unroll
        for (int e = 0; e < 8; ++e) vacc[e]     += (float)c0[e];
#pragma unroll
        for (int e = 0; e < 8; ++e) vacc[8 + e] += (float)c1[e];
        c0 = nx0; c1 = nx1;
    }
    {
        const float rL = 1.0f / L;
#pragma unroll
        for (int j = 0; j < 2; ++j) {
            bf16x8 o;
#pragma unroll
            for (int e = 0; e < 8; ++e) o[e] = (bf16)(vacc[j * 8 + e] * rL);
            const int c = (tid & 7) * 2 + j;
            *(bf16x8*)&cbuf[tn * 128 + ((c ^ (tn & 7)) * 8)] = o;
        }
    }
    __syncthreads();   // drains wbuf half-0 + cbuf ds_writes

    const float gm = gam[0];

    auto mfma_pass = [&](f32x4 (&acc)[2][2]) {
#pragma unroll
        for (int i = 0; i < 2; ++i)
#pragma unroll
            for (int j = 0; j < 2; ++j) acc[i][j] = (f32x4){0.f, 0.f, 0.f, 0.f};
#pragma unroll
        for (int kk = 0; kk < 4; ++kk) {
#pragma unroll
            for (int cot = 0; cot < 2; ++cot) {
                const int arow = wav * 32 + cot * 16 + l15;
                const bf16x8 af = *(const bf16x8*)&wbuf[arow * 128 + (((kk * 4 + quad) ^ (arow & 7)) * 8)];
#pragma unroll
                for (int nt = 0; nt < 2; ++nt) {
                    const int brow = nt * 16 + l15;
                    const bf16x8 bfc = *(const bf16x8*)&cbuf[brow * 128 + (((kk * 4 + quad) ^ (brow & 7)) * 8)];
                    acc[cot][nt] = __builtin_amdgcn_mfma_f32_16x16x32_bf16(af, bfc, acc[cot][nt], 0, 0, 0);
                }
            }
        }
    };
    auto store_pass = [&](const f32x4 (&acc)[2][2], int p) {
#pragma unroll
        for (int cot = 0; cot < 2; ++cot)
#pragma unroll
            for (int r = 0; r < 4; ++r) {
                const int co = p * 128 + wav * 32 + cot * 16 + quad * 4 + r;
                const float bv = W_b[co];
#pragma unroll
                for (int nt = 0; nt < 2; ++nt) {
                    const int n = n0 + nt * 16 + l15;
                    const size_t a = ((size_t)b * COd + co) * NN + n;
                    out[a] = gm * (acc[cot][nt][r] + bv) + x[a];
                }
            }
    };

    f32x4 acc0[2][2];
    mfma_pass(acc0);
    __syncthreads();          // all waves done reading wbuf half 0
    stage_w(1);               // issue half-1 writes ...
    store_pass(acc0, 0);      // ... overlapped with half-0 stores
    __syncthreads();          // drain half-1 ds_writes
    f32x4 acc1[2][2];
    mfma_pass(acc1);
    store_pass(acc1, 1);
}

// ---------------------------------------------------------------------------
extern "C" void kernel_launch(void* const* d_in, const int* in_sizes, int n_in,
                              void* d_out, int out_size, void* d_ws, size_t ws_size,
                              hipStream_t stream)
{
    const float* x     = (const float*)d_in[0];
    const float* y     = (const float*)d_in[1];
    const float* fk_w  = (const float*)d_in[2];
    const float* fk_g  = (const float*)d_in[3];
    const float* fk_b  = (const float*)d_in[4];
    const float* fk_m  = (const float*)d_in[5];
    const float* fk_v  = (const float*)d_in[6];
    const float* fq_w  = (const float*)d_in[7];
    const float* fq_g  = (const float*)d_in[8];
    const float* fq_b  = (const float*)d_in[9];
    const float* fq_m  = (const float*)d_in[10];
    const float* fq_v  = (const float*)d_in[11];
    const float* fv_w  = (const float*)d_in[12];
    const float* fv_b  = (const float*)d_in[13];
    const float* W_w   = (const float*)d_in[14];
    const float* W_b   = (const float*)d_in[15];
    const float* gamma = (const float*)d_in[16];
    float* out = (float*)d_out;

    char* ws = (char*)d_ws;
    size_t off = 0;
    auto carve = [&](size_t bytes) -> char* {
        char* p = ws + off;
        off = (off + bytes + 255) & ~(size_t)255;
        return p;
    };

    bf16*  kb   = (bf16*)carve((size_t)NB * NN * CKd * 2);
    bf16*  qbuf = (bf16*)carve((size_t)NB * NN * CKd * 2);
    bf16*  vb   = (bf16*)carve((size_t)NB * CVd * NN * 2);

    const size_t region = ws_size - off;
    const size_t per_ks = (size_t)NB * NN * CVd * 2 + (size_t)NB * NN * 4 + 512;
    int KS = 1;
    {
        // KS=5 -> attn grid 500 = 98% of the 512-slot capacity (2 blocks/CU
        // at 64 KB LDS), one dispatch round; pO = 16.4 MB.
        const int cand[4] = {5, 4, 2, 1};
        for (int i = 0; i < 4; ++i)
            if ((size_t)cand[i] * per_ks <= region) { KS = cand[i]; break; }
    }
    bf16*  pO = (bf16*)carve((size_t)KS * NB * NN * CVd * 2);
    float* pl = (float*)carve((size_t)KS * NB * NN * 4);

    const dim3 blk(256);
    projkqv_kernel<<<dim3(100, 4, NB), blk, 0, stream>>>(x, y,
                                                         fk_w, fk_g, fk_b, fk_m, fk_v,
                                                         fq_w, fq_g, fq_b, fq_m, fq_v,
                                                         fv_w, fv_b, kb, qbuf, vb);
    attn_kernel<<<dim3(50 * NB * KS), blk, 0, stream>>>(qbuf, kb, vb, pO, pl, KS);
    outproj_kernel<<<dim3(200, NB), blk, 0, stream>>>(pO, pl, W_w, W_b, x, gamma, out, KS);
}